// Round 16
// baseline (129.447 us; speedup 1.0000x reference)
//
#include <hip/hip_runtime.h>
#include <hip/hip_bf16.h>

#define NN 50000
#define FF 128
#define UU 128
#define NREL 8
#define NE 60000
#define NKEY (NREL * NN)        // 400000
#define NET (NREL * NE)         // 480000

typedef __attribute__((ext_vector_type(8))) short bf16x8;
typedef __attribute__((ext_vector_type(4))) float f32x4;

// ---------------- fused prep + build ----------------
// prep: X->bf16; W->fragment layout (for (m,c,s), a 1KB block at
// ((m*8+c)*4+s)*512 ushorts; lane (ag*16+al) holds 8 bf16 of
// W_m[k=s*32+ag*8+j][col=c*16+al]).
// build: per-(rel,dst) linked list via atomicExch (head pre-set to -1 by the
// stream-ordered memset); rec[i] = {src, w_bits, prev, pad}.

__global__ __launch_bounds__(256) void prepbuild_kernel(
    const float* __restrict__ X, const float* __restrict__ Wself,
    const float* __restrict__ Wrel, const int* __restrict__ esrc,
    const int* __restrict__ edst, const float* __restrict__ ew,
    ushort* __restrict__ Xb, ushort* __restrict__ Wf,
    int* __restrict__ head, int4* __restrict__ rec)
{
    int i = blockIdx.x * 256 + threadIdx.x;
    if (i < NN * FF / 4) {                      // X -> bf16
        float4 v = ((const float4*)X)[i];
        union { __hip_bfloat162 h[2]; uint2 u; } p;
        p.h[0] = __float22bfloat162_rn(make_float2(v.x, v.y));
        p.h[1] = __float22bfloat162_rn(make_float2(v.z, v.w));
        ((uint2*)Xb)[i] = p.u;
    }
    if (i < NET) {                              // linked-list build
        int key = (i / NE) * NN + edst[i];      // const divisor -> magic mul
        int prev = atomicExch(&head[key], i);
        rec[i] = make_int4(esrc[i], __float_as_int(ew[i]), prev, 0);
    }
    if (i < 9 * FF * UU) {                      // W -> fragment layout
        int m = i >> 14, k = (i >> 7) & 127, col = i & 127;
        int c = col >> 4, al = col & 15;
        int s = k >> 5, ag = (k >> 3) & 3, j = k & 7;
        float v = (m == 0) ? Wself[i] : Wrel[i - FF * UU];
        __hip_bfloat16 h = __float2bfloat16(v);
        Wf[((m * 8 + c) * 4 + s) * 512 + (ag * 16 + al) * 8 + j] = *(ushort*)&h;
    }
}

// ---------------- pass 1: aggregation (round-15 structure, best measured) -------
// One wave per 4 consecutive keys; first two list levels unrolled in parallel
// across the 4 walks; serial tail loop only for n>=3 (12% of keys).

#define AGG_L1R(i) int4 r##i = make_int4(0, 0, 0, 0); \
    if (e##i >= 0) r##i = rec[e##i];
#define AGG_L1X(i) uint x##i = 0u; \
    if (e##i >= 0) x##i = *(const uint*)(Xb + (size_t)r##i.x * FF + 2 * l);
#define AGG_L2R(i) int f##i = (e##i >= 0) ? r##i.z : -1; \
    int4 s##i = make_int4(0, 0, 0, 0); \
    if (f##i >= 0) s##i = rec[f##i];
#define AGG_L1A(i) if (e##i >= 0) { \
        float wgt = __int_as_float(r##i.y); \
        ax##i = fmaf(__uint_as_float(x##i << 16), wgt, ax##i); \
        ay##i = fmaf(__uint_as_float(x##i & 0xffff0000u), wgt, ay##i); }
#define AGG_L2X(i) uint y##i = 0u; \
    if (f##i >= 0) y##i = *(const uint*)(Xb + (size_t)s##i.x * FF + 2 * l);
#define AGG_L2A(i) if (f##i >= 0) { \
        float wgt = __int_as_float(s##i.y); \
        ax##i = fmaf(__uint_as_float(y##i << 16), wgt, ax##i); \
        ay##i = fmaf(__uint_as_float(y##i & 0xffff0000u), wgt, ay##i); \
        e##i = s##i.z; \
        if (e##i >= 0) r##i = rec[e##i]; \
    } else e##i = -1;

#define AGG_WALK(e, r, ax, ay)                                              \
    while (e >= 0) {                                                        \
        float w = __int_as_float(r.y);                                      \
        uint x = *(const uint*)(Xb + (size_t)r.x * FF + 2 * l);             \
        e = r.z;                                                            \
        if (e >= 0) r = rec[e];                                             \
        ax = fmaf(__uint_as_float(x << 16), w, ax);                         \
        ay = fmaf(__uint_as_float(x & 0xffff0000u), w, ay);                 \
    }

#define AGG_ST(i) { \
        __hip_bfloat162 hh = __float22bfloat162_rn(make_float2(ax##i, ay##i)); \
        *(uint*)(Zb + (size_t)(k0 + i) * FF + 2 * l) = *(uint*)&hh; }

__global__ __launch_bounds__(256) void agg_kernel(
    const ushort* __restrict__ Xb, const int* __restrict__ head,
    const int4* __restrict__ rec, ushort* __restrict__ Zb)
{
    const int k0 = ((blockIdx.x * 256 + threadIdx.x) >> 6) * 4;
    const int l = threadIdx.x & 63;

    float ax0 = 0.f, ay0 = 0.f, ax1 = 0.f, ay1 = 0.f;
    float ax2 = 0.f, ay2 = 0.f, ax3 = 0.f, ay3 = 0.f;

    const int4 hv = *(const int4*)&head[k0];
    int e0 = hv.x, e1 = hv.y, e2 = hv.z, e3 = hv.w;

    AGG_L1R(0) AGG_L1R(1) AGG_L1R(2) AGG_L1R(3)
    AGG_L1X(0) AGG_L1X(1) AGG_L1X(2) AGG_L1X(3)
    AGG_L2R(0) AGG_L2R(1) AGG_L2R(2) AGG_L2R(3)
    AGG_L1A(0) AGG_L1A(1) AGG_L1A(2) AGG_L1A(3)
    AGG_L2X(0) AGG_L2X(1) AGG_L2X(2) AGG_L2X(3)
    AGG_L2A(0) AGG_L2A(1) AGG_L2A(2) AGG_L2A(3)

    AGG_WALK(e0, r0, ax0, ay0)
    AGG_WALK(e1, r1, ax1, ay1)
    AGG_WALK(e2, r2, ax2, ay2)
    AGG_WALK(e3, r3, ax3, ay3)

    AGG_ST(0) AGG_ST(1) AGG_ST(2) AGG_ST(3)
}

// ---------------- pass 2: GEMM, 32 rows/wave, W via global_load_lds ------------
// Block = 2 waves (128 thr), wave = TWO 16-row tiles (R0..R0+15, R0+16..R0+31).
// Per m: 16 global_load_lds_dwordx4/thread stage the 32KB W plane into LDS;
// A[m+1] frags (both tiles) load into off-parity regs in the same window; one
// barrier drain covers both. Each B-frag ds_read feeds TWO MFMAs (acc0/acc1)
// -> ds_read per MFMA halved vs round 15. Tail waves clamp load rows, guard
// stores. D: col = c*16+al, row = R0(+16) + ag*4 + q (verified rounds 5-15).

__device__ __forceinline__ void gload_lds16(const uint4* g, uint4* l) {
    __builtin_amdgcn_global_load_lds(
        (const __attribute__((address_space(1))) void*)g,
        (__attribute__((address_space(3))) void*)l, 16, 0, 0);
}

#define LOAD_A(AF, P)                                                        \
    _Pragma("unroll")                                                        \
    for (int s = 0; s < 4; ++s)                                              \
        AF[s] = *(const bf16x8*)((P) + s * 32 + ag * 8);

#define MFMA_BURST2(AF0, AF1)                                                \
    _Pragma("unroll")                                                        \
    for (int c = 0; c < 8; ++c) {                                            \
        _Pragma("unroll")                                                    \
        for (int s = 0; s < 4; ++s) {                                        \
            bf16x8 bfr = *(const bf16x8*)&bsh[(c * 4 + s) * 64 + l];         \
            acc0[c] = __builtin_amdgcn_mfma_f32_16x16x32_bf16(               \
                AF0[s], bfr, acc0[c], 0, 0, 0);                              \
            acc1[c] = __builtin_amdgcn_mfma_f32_16x16x32_bf16(               \
                AF1[s], bfr, acc1[c], 0, 0, 0);                              \
        }                                                                    \
    }

__global__ __launch_bounds__(128, 3) void gemm_kernel(
    const ushort* __restrict__ Xb, const ushort* __restrict__ Zb,
    const ushort* __restrict__ Wf, const float* __restrict__ bias,
    float* __restrict__ out)
{
    __shared__ uint4 bsh[2048];                 // 32 KB: one Wf plane
    const int t = threadIdx.x;
    const int wid = t >> 6;
    const int l = t & 63;
    const int gw = blockIdx.x * 2 + wid;        // wave id, 32 rows each
    const int R0 = gw * 32;
    const int al = l & 15;
    const int ag = l >> 4;

    // clamped load rows (tail waves read row NN-1; stores are guarded)
    const int r0 = (R0 + al < NN) ? R0 + al : NN - 1;
    const int r1 = (R0 + 16 + al < NN) ? R0 + 16 + al : NN - 1;

    const uint4* Wf4 = (const uint4*)Wf;

    f32x4 acc0[8], acc1[8];
    #pragma unroll
    for (int c = 0; c < 8; ++c) {
        acc0[c] = (f32x4){0.f, 0.f, 0.f, 0.f};
        acc1[c] = (f32x4){0.f, 0.f, 0.f, 0.f};
    }

    bf16x8 a0A[4], a1A[4], a0B[4], a1B[4];
    LOAD_A(a0A, Xb + (size_t)r0 * FF)
    LOAD_A(a1A, Xb + (size_t)r1 * FF)

    #pragma unroll
    for (int m = 0; m < 9; ++m) {
        __syncthreads();                        // prev MFMA done reading bsh
        {                                       // W[m] -> LDS via DMA
            const uint4* Wm = Wf4 + m * 2048 + wid * 64 + l;   // per-lane src
            uint4* lb = &bsh[wid * 64];                        // wave-uniform
            #pragma unroll
            for (int k = 0; k < 16; ++k)
                gload_lds16(Wm + k * 128, lb + k * 128);
        }
        if (m < 8) {                            // prefetch A[m+1] (Zb plane m)
            const ushort* Zm = Zb + (size_t)m * NN * FF;
            if ((m & 1) == 0) {
                LOAD_A(a0B, Zm + (size_t)r0 * FF)
                LOAD_A(a1B, Zm + (size_t)r1 * FF)
            } else {
                LOAD_A(a0A, Zm + (size_t)r0 * FF)
                LOAD_A(a1A, Zm + (size_t)r1 * FF)
            }
        }
        __syncthreads();                        // drains DMA + A loads
        if ((m & 1) == 0) { MFMA_BURST2(a0A, a1A) } else { MFMA_BURST2(a0B, a1B) }
    }

    #pragma unroll
    for (int c = 0; c < 8; ++c) {
        int col = c * 16 + al;
        float b = bias[col];
        #pragma unroll
        for (int q = 0; q < 4; ++q) {
            int row = R0 + ag * 4 + q;
            if (row < NN)
                out[(size_t)row * UU + col] = fmaxf(acc0[c][q] + b, 0.f);
            int row2 = R0 + 16 + ag * 4 + q;
            if (row2 < NN)
                out[(size_t)row2 * UU + col] = fmaxf(acc1[c][q] + b, 0.f);
        }
    }
}

// ---------------- launch ----------------

extern "C" void kernel_launch(void* const* d_in, const int* in_sizes, int n_in,
                              void* d_out, int out_size, void* d_ws, size_t ws_size,
                              hipStream_t stream) {
    const float* X     = (const float*)d_in[0];
    const int*   esrc  = (const int*)d_in[1];
    const int*   edst  = (const int*)d_in[2];
    const float* ew    = (const float*)d_in[3];
    const float* Wself = (const float*)d_in[4];
    const float* Wrel  = (const float*)d_in[5];
    const float* bias  = (const float*)d_in[6];
    float* out = (float*)d_out;

    // ws layout (16B-aligned segments), ~125 MB total
    ushort* Zb   = (ushort*)d_ws;               // NKEY*FF bf16 = 102.4 MB
    ushort* Xb   = Zb + (size_t)NKEY * FF;      // NN*FF bf16   = 12.8 MB
    ushort* Wf   = Xb + (size_t)NN * FF;        // 9*FF*UU bf16 = 0.29 MB
    int*    head = (int*)(Wf + 9 * FF * UU);    // NKEY         = 1.6 MB
    int4*   rec  = (int4*)(head + NKEY);        // NET int4     = 7.7 MB

    hipMemsetAsync(head, 0xFF, NKEY * sizeof(int), stream);   // head = -1
    hipLaunchKernelGGL(prepbuild_kernel, dim3(NN * FF / 4 / 256), dim3(256), 0, stream,
                       X, Wself, Wrel, esrc, edst, ew, Xb, Wf, head, rec);
    hipLaunchKernelGGL(agg_kernel,  dim3(NKEY / 16), dim3(256), 0, stream,
                       Xb, head, rec, Zb);
    // 1563 waves of 32 rows, 2 waves/block
    hipLaunchKernelGGL(gemm_kernel, dim3((NN / 32 + 2) / 2), dim3(128), 0, stream,
                       Xb, Zb, Wf, bias, out);
}

// Round 17
// 119.718 us; speedup vs baseline: 1.0813x; 1.0813x over previous
//
#include <hip/hip_runtime.h>
#include <hip/hip_bf16.h>

#define NN 50000
#define FF 128
#define UU 128
#define NREL 8
#define NE 60000
#define NKEY (NREL * NN)        // 400000
#define NET (NREL * NE)         // 480000

typedef __attribute__((ext_vector_type(8))) short bf16x8;
typedef __attribute__((ext_vector_type(4))) float f32x4;

// ---------------- fused prep + build ----------------
// prep: X->bf16; W->fragment layout (for (m,c,s), a 1KB block at
// ((m*8+c)*4+s)*512 ushorts; lane (ag*16+al) holds 8 bf16 of
// W_m[k=s*32+ag*8+j][col=c*16+al]).
// build: per-(rel,dst) linked list via atomicExch (head pre-set to -1 by the
// stream-ordered memset); rec[i] = {src, w_bits, prev, pad}.

__global__ __launch_bounds__(256) void prepbuild_kernel(
    const float* __restrict__ X, const float* __restrict__ Wself,
    const float* __restrict__ Wrel, const int* __restrict__ esrc,
    const int* __restrict__ edst, const float* __restrict__ ew,
    ushort* __restrict__ Xb, ushort* __restrict__ Wf,
    int* __restrict__ head, int4* __restrict__ rec)
{
    int i = blockIdx.x * 256 + threadIdx.x;
    if (i < NN * FF / 4) {                      // X -> bf16
        float4 v = ((const float4*)X)[i];
        union { __hip_bfloat162 h[2]; uint2 u; } p;
        p.h[0] = __float22bfloat162_rn(make_float2(v.x, v.y));
        p.h[1] = __float22bfloat162_rn(make_float2(v.z, v.w));
        ((uint2*)Xb)[i] = p.u;
    }
    if (i < NET) {                              // linked-list build
        int key = (i / NE) * NN + edst[i];      // const divisor -> magic mul
        int prev = atomicExch(&head[key], i);
        rec[i] = make_int4(esrc[i], __float_as_int(ew[i]), prev, 0);
    }
    if (i < 9 * FF * UU) {                      // W -> fragment layout
        int m = i >> 14, k = (i >> 7) & 127, col = i & 127;
        int c = col >> 4, al = col & 15;
        int s = k >> 5, ag = (k >> 3) & 3, j = k & 7;
        float v = (m == 0) ? Wself[i] : Wrel[i - FF * UU];
        __hip_bfloat16 h = __float2bfloat16(v);
        Wf[((m * 8 + c) * 4 + s) * 512 + (ag * 16 + al) * 8 + j] = *(ushort*)&h;
    }
}

// ---------------- pass 1: aggregation (r15 walker + empty-key store skip) -------
// One wave per 4 consecutive keys; first two list levels unrolled in parallel
// across the 4 walks; serial tail loop only for n>=3. Keys with no edges skip
// the Zb store entirely (gemm masks them via head flags).

#define AGG_L1R(i) int4 r##i = make_int4(0, 0, 0, 0); \
    if (e##i >= 0) r##i = rec[e##i];
#define AGG_L1X(i) uint x##i = 0u; \
    if (e##i >= 0) x##i = *(const uint*)(Xb + (size_t)r##i.x * FF + 2 * l);
#define AGG_L2R(i) int f##i = (e##i >= 0) ? r##i.z : -1; \
    int4 s##i = make_int4(0, 0, 0, 0); \
    if (f##i >= 0) s##i = rec[f##i];
#define AGG_L1A(i) if (e##i >= 0) { \
        float wgt = __int_as_float(r##i.y); \
        ax##i = fmaf(__uint_as_float(x##i << 16), wgt, ax##i); \
        ay##i = fmaf(__uint_as_float(x##i & 0xffff0000u), wgt, ay##i); }
#define AGG_L2X(i) uint y##i = 0u; \
    if (f##i >= 0) y##i = *(const uint*)(Xb + (size_t)s##i.x * FF + 2 * l);
#define AGG_L2A(i) if (f##i >= 0) { \
        float wgt = __int_as_float(s##i.y); \
        ax##i = fmaf(__uint_as_float(y##i << 16), wgt, ax##i); \
        ay##i = fmaf(__uint_as_float(y##i & 0xffff0000u), wgt, ay##i); \
        e##i = s##i.z; \
        if (e##i >= 0) r##i = rec[e##i]; \
    } else e##i = -1;

#define AGG_WALK(e, r, ax, ay)                                              \
    while (e >= 0) {                                                        \
        float w = __int_as_float(r.y);                                      \
        uint x = *(const uint*)(Xb + (size_t)r.x * FF + 2 * l);             \
        e = r.z;                                                            \
        if (e >= 0) r = rec[e];                                             \
        ax = fmaf(__uint_as_float(x << 16), w, ax);                         \
        ay = fmaf(__uint_as_float(x & 0xffff0000u), w, ay);                 \
    }

#define AGG_ST(i) { \
        __hip_bfloat162 hh = __float22bfloat162_rn(make_float2(ax##i, ay##i)); \
        *(uint*)(Zb + (size_t)(k0 + i) * FF + 2 * l) = *(uint*)&hh; }

__global__ __launch_bounds__(256) void agg_kernel(
    const ushort* __restrict__ Xb, const int* __restrict__ head,
    const int4* __restrict__ rec, ushort* __restrict__ Zb)
{
    const int k0 = ((blockIdx.x * 256 + threadIdx.x) >> 6) * 4;
    const int l = threadIdx.x & 63;

    float ax0 = 0.f, ay0 = 0.f, ax1 = 0.f, ay1 = 0.f;
    float ax2 = 0.f, ay2 = 0.f, ax3 = 0.f, ay3 = 0.f;

    const int4 hv = *(const int4*)&head[k0];
    int e0 = hv.x, e1 = hv.y, e2 = hv.z, e3 = hv.w;

    AGG_L1R(0) AGG_L1R(1) AGG_L1R(2) AGG_L1R(3)
    AGG_L1X(0) AGG_L1X(1) AGG_L1X(2) AGG_L1X(3)
    AGG_L2R(0) AGG_L2R(1) AGG_L2R(2) AGG_L2R(3)
    AGG_L1A(0) AGG_L1A(1) AGG_L1A(2) AGG_L1A(3)
    AGG_L2X(0) AGG_L2X(1) AGG_L2X(2) AGG_L2X(3)
    AGG_L2A(0) AGG_L2A(1) AGG_L2A(2) AGG_L2A(3)

    AGG_WALK(e0, r0, ax0, ay0)
    AGG_WALK(e1, r1, ax1, ay1)
    AGG_WALK(e2, r2, ax2, ay2)
    AGG_WALK(e3, r3, ax3, ay3)

    // store only non-empty keys (wave-uniform conditions)
    if (hv.x >= 0) AGG_ST(0)
    if (hv.y >= 0) AGG_ST(1)
    if (hv.z >= 0) AGG_ST(2)
    if (hv.w >= 0) AGG_ST(3)
}

// ---------------- pass 2: GEMM (r15 structure + empty-row masked A loads) ------
// Block = 4 waves, wave = one 16-row tile. Per m: 8 global_load_lds_dwordx4
// per thread stage the 32KB W plane into LDS (wave-uniform LDS base +
// per-lane global src), A[m+1] frags load into off-parity regs in the same
// window, one drain at the barrier covers both. Per-lane head-flag bitmask
// (preloaded, latencies overlapped) masks A-frags of empty Zb rows — their
// (unwritten, poisoned) memory is never read. D: col=c*16+al, row=R0+ag*4+q.

__device__ __forceinline__ void gload_lds16(const uint4* g, uint4* l) {
    __builtin_amdgcn_global_load_lds(
        (const __attribute__((address_space(1))) void*)g,
        (__attribute__((address_space(3))) void*)l, 16, 0, 0);
}

#define LOAD_A(AF, P)                                                        \
    _Pragma("unroll")                                                        \
    for (int s = 0; s < 4; ++s)                                              \
        AF[s] = *(const bf16x8*)((P) + s * 32 + ag * 8);

#define LOAD_A_P(AF, P, NZ)                                                  \
    _Pragma("unroll")                                                        \
    for (int s = 0; s < 4; ++s) AF[s] = zfrag;                               \
    if (NZ) {                                                                \
        _Pragma("unroll")                                                    \
        for (int s = 0; s < 4; ++s)                                          \
            AF[s] = *(const bf16x8*)((P) + s * 32 + ag * 8);                 \
    }

#define MFMA_BURST(AF)                                                       \
    _Pragma("unroll")                                                        \
    for (int c = 0; c < 8; ++c) {                                            \
        _Pragma("unroll")                                                    \
        for (int s = 0; s < 4; ++s) {                                        \
            bf16x8 bfr = *(const bf16x8*)&bsh[(c * 4 + s) * 64 + l];         \
            acc[c] = __builtin_amdgcn_mfma_f32_16x16x32_bf16(                \
                AF[s], bfr, acc[c], 0, 0, 0);                                \
        }                                                                    \
    }

__global__ __launch_bounds__(256, 4) void gemm_kernel(
    const ushort* __restrict__ Xb, const ushort* __restrict__ Zb,
    const ushort* __restrict__ Wf, const int* __restrict__ head,
    const float* __restrict__ bias, float* __restrict__ out)
{
    __shared__ uint4 bsh[2048];                 // 32 KB: one Wf plane
    const int t = threadIdx.x;
    const int wid = t >> 6;
    const int l = t & 63;
    const int gw0 = blockIdx.x * 4 + wid;
    const int gwid = (gw0 < NN / 16) ? gw0 : NN / 16 - 1;  // dup tail, benign
    const int R0 = gwid * 16;
    const int al = l & 15;
    const int ag = l >> 4;
    const int arow = R0 + al;                   // this lane's A row

    const uint4* Wf4 = (const uint4*)Wf;
    const bf16x8 zfrag = {0, 0, 0, 0, 0, 0, 0, 0};

    f32x4 acc[8];
    #pragma unroll
    for (int c = 0; c < 8; ++c) acc[c] = (f32x4){0.f, 0.f, 0.f, 0.f};

    // preload all 8 empty-row flags (independent gathers, latencies overlap)
    uint nzmask = 0;
    #pragma unroll
    for (int mm = 0; mm < 8; ++mm)
        if (head[(size_t)mm * NN + arow] >= 0) nzmask |= (1u << mm);

    bf16x8 aA[4], aB[4];
    {
        const ushort* A0 = Xb + (size_t)arow * FF;
        LOAD_A(aA, A0)
    }

    #pragma unroll
    for (int m = 0; m < 9; ++m) {
        __syncthreads();                        // prev MFMA done reading bsh
        {                                       // W[m] -> LDS via DMA
            const uint4* Wm = Wf4 + m * 2048 + wid * 64 + l;   // per-lane src
            uint4* lb = &bsh[wid * 64];                        // wave-uniform
            #pragma unroll
            for (int k = 0; k < 8; ++k)
                gload_lds16(Wm + k * 256, lb + k * 256);
        }
        if (m < 8) {                            // prefetch A[m+1] (Zb plane m)
            const ushort* An = Zb + ((size_t)m * NN + arow) * FF;
            const bool nz = (nzmask >> m) & 1;
            if ((m & 1) == 0) { LOAD_A_P(aB, An, nz) } else { LOAD_A_P(aA, An, nz) }
        }
        __syncthreads();                        // drains DMA + A loads
        if ((m & 1) == 0) { MFMA_BURST(aA) } else { MFMA_BURST(aB) }
    }

    #pragma unroll
    for (int c = 0; c < 8; ++c) {
        int col = c * 16 + al;
        float b = bias[col];
        #pragma unroll
        for (int q = 0; q < 4; ++q) {
            int row = R0 + ag * 4 + q;
            out[(size_t)row * UU + col] = fmaxf(acc[c][q] + b, 0.f);
        }
    }
}

// ---------------- launch ----------------

extern "C" void kernel_launch(void* const* d_in, const int* in_sizes, int n_in,
                              void* d_out, int out_size, void* d_ws, size_t ws_size,
                              hipStream_t stream) {
    const float* X     = (const float*)d_in[0];
    const int*   esrc  = (const int*)d_in[1];
    const int*   edst  = (const int*)d_in[2];
    const float* ew    = (const float*)d_in[3];
    const float* Wself = (const float*)d_in[4];
    const float* Wrel  = (const float*)d_in[5];
    const float* bias  = (const float*)d_in[6];
    float* out = (float*)d_out;

    // ws layout (16B-aligned segments), ~125 MB total
    ushort* Zb   = (ushort*)d_ws;               // NKEY*FF bf16 = 102.4 MB
    ushort* Xb   = Zb + (size_t)NKEY * FF;      // NN*FF bf16   = 12.8 MB
    ushort* Wf   = Xb + (size_t)NN * FF;        // 9*FF*UU bf16 = 0.29 MB
    int*    head = (int*)(Wf + 9 * FF * UU);    // NKEY         = 1.6 MB
    int4*   rec  = (int4*)(head + NKEY);        // NET int4     = 7.7 MB

    hipMemsetAsync(head, 0xFF, NKEY * sizeof(int), stream);   // head = -1
    hipLaunchKernelGGL(prepbuild_kernel, dim3(NN * FF / 4 / 256), dim3(256), 0, stream,
                       X, Wself, Wrel, esrc, edst, ew, Xb, Wf, head, rec);
    hipLaunchKernelGGL(agg_kernel,  dim3(NKEY / 16), dim3(256), 0, stream,
                       Xb, head, rec, Zb);
    hipLaunchKernelGGL(gemm_kernel, dim3((NN / 16 + 3) / 4), dim3(256), 0, stream,
                       Xb, Zb, Wf, head, bias, out);
}